// Round 1
// baseline (191.470 us; speedup 1.0000x reference)
//
#include <hip/hip_runtime.h>
#include <stdint.h>

#define NB 8
#define CC 512
#define PP 2304
#define EPSF 1e-5f

typedef short bf16x8 __attribute__((ext_vector_type(8)));
typedef float f32x4 __attribute__((ext_vector_type(4)));

__device__ __forceinline__ float bf2f(uint32_t b16) {
  return __uint_as_float(b16 << 16);
}
__device__ __forceinline__ uint32_t f2bf(float f) {  // RNE
  uint32_t u = __float_as_uint(f);
  return (u + 0x7fffu + ((u >> 16) & 1u)) >> 16;
}

// ---------------- K1: channel mean of target over (N,H,W) ----------------
__global__ __launch_bounds__(256) void k_chan_mean(const float* __restrict__ tgt,
                                                   float* __restrict__ mu) {
  const int c = blockIdx.x, t = threadIdx.x;
  float s = 0.f;
  for (int n = 0; n < NB; ++n) {
    const float* b = tgt + ((size_t)n * CC + c) * PP;
    for (int p = t; p < PP; p += 256) s += b[p];
  }
  for (int off = 32; off; off >>= 1) s += __shfl_down(s, off);
  __shared__ float red[4];
  if ((t & 63) == 0) red[t >> 6] = s;
  __syncthreads();
  if (t == 0) mu[c] = (red[0] + red[1] + red[2] + red[3]) * (1.0f / (NB * PP));
}

// ------- K2: center by mu, cast bf16, transpose [N][C][P]->[N][P][C], sumsq over C -------
__global__ __launch_bounds__(256) void k_center_cast(
    const float* __restrict__ pred, const float* __restrict__ tgt,
    const float* __restrict__ mu,
    uint16_t* __restrict__ xt, uint16_t* __restrict__ yt,
    float* __restrict__ ssx, float* __restrict__ ssy) {
  __shared__ uint32_t lt[64][33];   // [p][c-pair], +1 pad -> conflict-free
  __shared__ float red[4][64];
  const int p0 = blockIdx.x * 64, c0 = blockIdx.y * 64, n = blockIdx.z;
  const int t = threadIdx.x, lp = t & 63, cb = t >> 6;
  for (int which = 0; which < 2; ++which) {
    const float* in = which ? tgt : pred;
    uint16_t* out = which ? yt : xt;
    float* ss = which ? ssy : ssx;
    float sq = 0.f;
    uint32_t packs[8];
#pragma unroll
    for (int i = 0; i < 16; ++i) {
      const int c = c0 + cb * 16 + i;
      float v = in[((size_t)n * CC + c) * PP + p0 + lp] - mu[c];
      sq += v * v;
      uint32_t b = f2bf(v);
      if (i & 1) packs[i >> 1] |= b << 16; else packs[i >> 1] = b;
    }
#pragma unroll
    for (int j = 0; j < 8; ++j) lt[lp][cb * 8 + j] = packs[j];
    red[cb][lp] = sq;
    __syncthreads();
    if (t < 64)
      atomicAdd(&ss[(size_t)n * PP + p0 + t],
                red[0][t] + red[1][t] + red[2][t] + red[3][t]);
    // write-out: thread t -> row p0+(t>>2), 16 contiguous c's
    const int p = t >> 2, ch = t & 3;
    uint4 v0, v1;
    v0.x = lt[p][ch * 8 + 0]; v0.y = lt[p][ch * 8 + 1];
    v0.z = lt[p][ch * 8 + 2]; v0.w = lt[p][ch * 8 + 3];
    v1.x = lt[p][ch * 8 + 4]; v1.y = lt[p][ch * 8 + 5];
    v1.z = lt[p][ch * 8 + 6]; v1.w = lt[p][ch * 8 + 7];
    uint4* ob = (uint4*)(out + (((size_t)n * PP + p0 + p) * CC + c0 + ch * 16));
    ob[0] = v0; ob[1] = v1;
    __syncthreads();
  }
}

// ---------------- K2.5: inverse norms (ssx,ssy contiguous -> invx,invy contiguous) ----------------
__global__ __launch_bounds__(256) void k_invnorm(const float* __restrict__ ss,
                                                 float* __restrict__ inv) {
  int i = blockIdx.x * 256 + threadIdx.x;
  if (i < 2 * NB * PP) inv[i] = 1.0f / fmaxf(sqrtf(ss[i]), 1e-12f);
}

// ---------------- K3: batched GEMM S[p][q] = sum_c X[p][c]*Y[q][c], scaled epilogue ----------------
__global__ __launch_bounds__(256) void k_gemm(
    const uint16_t* __restrict__ xt, const uint16_t* __restrict__ yt,
    const float* __restrict__ invx, const float* __restrict__ invy,
    uint16_t* __restrict__ S) {
  __shared__ uint16_t As[128 * 64];  // [row][k] bf16, 16B-slot XOR swizzle (slot^=row&7)
  __shared__ uint16_t Bs[128 * 64];
  const int nb = blockIdx.z;
  const int m0 = blockIdx.x * 128, n0 = blockIdx.y * 128;
  const int t = threadIdx.x, lane = t & 63, wid = t >> 6;
  const int wr = wid >> 1, wc = wid & 1;
  const uint16_t* Ax = xt + (size_t)nb * PP * CC;
  const uint16_t* By = yt + (size_t)nb * PP * CC;
  const int ric = lane >> 3;   // row within 8-row chunk
  const int slot = lane & 7;   // 16B slot within 128B k-row
  f32x4 acc[4][4];
#pragma unroll
  for (int i = 0; i < 4; ++i)
#pragma unroll
    for (int j = 0; j < 4; ++j) acc[i][j] = (f32x4){0.f, 0.f, 0.f, 0.f};

  for (int k0 = 0; k0 < CC; k0 += 64) {
    __syncthreads();
#pragma unroll
    for (int j = 0; j < 4; ++j) {
      const int row = (wid * 4 + j) * 8 + ric;           // 0..127
      const int ssw = (slot ^ (row & 7)) << 4;           // swizzled byte slot
      uint4 va = *(const uint4*)(Ax + (size_t)(m0 + row) * CC + k0 + slot * 8);
      uint4 vb = *(const uint4*)(By + (size_t)(n0 + row) * CC + k0 + slot * 8);
      *(uint4*)((char*)As + row * 128 + ssw) = va;
      *(uint4*)((char*)Bs + row * 128 + ssw) = vb;
    }
    __syncthreads();
#pragma unroll
    for (int kk = 0; kk < 2; ++kk) {
      const int kb = kk * 64 + (lane >> 4) * 16;  // byte offset of this lane's 8 bf16
      bf16x8 af[4], bfr[4];
#pragma unroll
      for (int mi = 0; mi < 4; ++mi) {
        const int row = wr * 64 + mi * 16 + (lane & 15);
        af[mi] = *(const bf16x8*)((const char*)As + row * 128 + (kb ^ ((row & 7) << 4)));
      }
#pragma unroll
      for (int ni = 0; ni < 4; ++ni) {
        const int row = wc * 64 + ni * 16 + (lane & 15);
        bfr[ni] = *(const bf16x8*)((const char*)Bs + row * 128 + (kb ^ ((row & 7) << 4)));
      }
#pragma unroll
      for (int mi = 0; mi < 4; ++mi)
#pragma unroll
        for (int ni = 0; ni < 4; ++ni)
          acc[mi][ni] = __builtin_amdgcn_mfma_f32_16x16x32_bf16(
              af[mi], bfr[ni], acc[mi][ni], 0, 0, 0);
    }
  }
  // epilogue: scale by inverse norms, write bf16 cosine
  const float* rip = invx + (size_t)nb * PP;
  const float* cip = invy + (size_t)nb * PP;
  float rinv[4][4], cinv[4];
#pragma unroll
  for (int mi = 0; mi < 4; ++mi)
#pragma unroll
    for (int r = 0; r < 4; ++r)
      rinv[mi][r] = rip[m0 + wr * 64 + mi * 16 + (lane >> 4) * 4 + r];
#pragma unroll
  for (int ni = 0; ni < 4; ++ni)
    cinv[ni] = cip[n0 + wc * 64 + ni * 16 + (lane & 15)];
  uint16_t* Sp = S + (size_t)nb * PP * PP;
#pragma unroll
  for (int mi = 0; mi < 4; ++mi) {
#pragma unroll
    for (int r = 0; r < 4; ++r) {
      const int grow = m0 + wr * 64 + mi * 16 + (lane >> 4) * 4 + r;
      uint16_t* rowp = Sp + (size_t)grow * PP + n0 + wc * 64 + (lane & 15);
#pragma unroll
      for (int ni = 0; ni < 4; ++ni) {
        float v = acc[mi][ni][r] * rinv[mi][r] * cinv[ni];
        rowp[ni * 16] = (uint16_t)f2bf(v);
      }
    }
  }
}

// ---------------- K4: per-row (n,p): dmin = 1 - max_q cos ; rowsum = sum_q w ----------------
__global__ __launch_bounds__(256) void k_rowstats(const uint16_t* __restrict__ S,
                                                  float* __restrict__ dmin,
                                                  float* __restrict__ rsum) {
  const int row = blockIdx.x;  // n*PP + p
  const uint32_t* Sp = (const uint32_t*)(S + (size_t)row * PP);
  __shared__ float cosr[PP];
  __shared__ float reda[4], redb[4];
  const int t = threadIdx.x;
  float mx = -2.f;
  for (int i = t; i < PP / 2; i += 256) {
    uint32_t u = Sp[i];
    float a = bf2f(u & 0xffffu), b = bf2f(u >> 16);
    *(float2*)&cosr[2 * i] = make_float2(a, b);
    mx = fmaxf(mx, fmaxf(a, b));
  }
  for (int off = 32; off; off >>= 1) mx = fmaxf(mx, __shfl_down(mx, off));
  if ((t & 63) == 0) reda[t >> 6] = mx;
  __syncthreads();
  mx = fmaxf(fmaxf(reda[0], reda[1]), fmaxf(reda[2], reda[3]));
  const float dm = 1.0f - mx;
  const float sc = 2.0f / (dm + EPSF);  // (1-dist_tilde)/0.5 = (cos-mx+eps)*sc
  float s = 0.f;
  for (int i = t; i < PP; i += 256) s += __expf((cosr[i] - mx + EPSF) * sc);
  for (int off = 32; off; off >>= 1) s += __shfl_down(s, off);
  if ((t & 63) == 0) redb[t >> 6] = s;
  __syncthreads();
  if (t == 0) { dmin[row] = dm; rsum[row] = redb[0] + redb[1] + redb[2] + redb[3]; }
}

// ---------------- K5a: partial colmax over p-chunks of cx = w/rowsum ----------------
__global__ __launch_bounds__(256) void k_colmax_part(const uint16_t* __restrict__ S,
                                                     const float* __restrict__ dmin,
                                                     const float* __restrict__ rsum,
                                                     float* __restrict__ pcm) {
  const int n = blockIdx.y, pc = blockIdx.z, t = threadIdx.x;
  const int q = blockIdx.x * 256 + t;
  __shared__ float lmx[384], lsc[384], lri[384];
  const float* dmn = dmin + (size_t)n * PP;
  const float* rsn = rsum + (size_t)n * PP;
  for (int i = t; i < 384; i += 256) {
    float dm = dmn[pc * 384 + i];
    lmx[i] = 1.0f - dm - EPSF;
    lsc[i] = 2.0f / (dm + EPSF);
    lri[i] = 1.0f / rsn[pc * 384 + i];
  }
  __syncthreads();
  const uint16_t* Sn = S + (size_t)n * PP * PP + (size_t)pc * 384 * PP + q;
  float best = 0.f;
  for (int p = 0; p < 384; ++p) {
    float c = bf2f((uint32_t)Sn[(size_t)p * PP]);
    best = fmaxf(best, __expf((c - lmx[p]) * lsc[p]) * lri[p]);
  }
  pcm[((size_t)n * 6 + pc) * PP + q] = best;
}

// ---------------- K5b: finish colmax, sum over q, accumulate per-n ----------------
__global__ __launch_bounds__(256) void k_colmax_fin(const float* __restrict__ pcm,
                                                    float* __restrict__ cxacc) {
  const int n = blockIdx.y, t = threadIdx.x;
  const int q = blockIdx.x * 256 + t;
  float best = 0.f;
  for (int c = 0; c < 6; ++c) best = fmaxf(best, pcm[((size_t)n * 6 + c) * PP + q]);
  float s = best;
  for (int off = 32; off; off >>= 1) s += __shfl_down(s, off);
  __shared__ float red[4];
  if ((t & 63) == 0) red[t >> 6] = s;
  __syncthreads();
  if (t == 0) atomicAdd(&cxacc[n], red[0] + red[1] + red[2] + red[3]);
}

// ---------------- K6: final loss ----------------
__global__ void k_final(const float* __restrict__ cxacc, float* __restrict__ out) {
  if (threadIdx.x == 0 && blockIdx.x == 0) {
    float s = 0.f;
    for (int n = 0; n < NB; ++n) {
      float cx = cxacc[n] * (1.0f / PP);
      s += -logf(cx + EPSF);
    }
    out[0] = s * (1.0f / NB);
  }
}

extern "C" void kernel_launch(void* const* d_in, const int* in_sizes, int n_in,
                              void* d_out, int out_size, void* d_ws, size_t ws_size,
                              hipStream_t stream) {
  const float* pred = (const float*)d_in[0];
  const float* tgt  = (const float*)d_in[1];
  float* W = (float*)d_ws;
  // workspace layout (float indices); total need ~118 MB
  float* mu   = W + 0;        // 512
  float* ssx  = W + 1024;     // 18432
  float* ssy  = W + 19456;    // 18432  (contiguous with ssx)
  float* cx   = W + 37888;    // 8
  float* invx = W + 38400;    // 18432
  float* invy = W + 56832;    // 18432  (contiguous with invx)
  float* dmin = W + 75264;    // 18432
  float* rsum = W + 93696;    // 18432
  float* pcm  = W + 112640;   // 110592 (8*6*2304)
  uint16_t* xt = (uint16_t*)(W + 223744);          // 9437184 bf16
  uint16_t* yt = xt + (size_t)NB * PP * CC;        // 9437184 bf16
  uint16_t* S  = yt + (size_t)NB * PP * CC;        // 42467328 bf16

  // zero atomic accumulators: ssx, ssy, cx
  hipMemsetAsync(W + 1024, 0, (36872) * sizeof(float), stream);

  k_chan_mean<<<dim3(CC), dim3(256), 0, stream>>>(tgt, mu);
  k_center_cast<<<dim3(PP / 64, CC / 64, NB), dim3(256), 0, stream>>>(
      pred, tgt, mu, xt, yt, ssx, ssy);
  k_invnorm<<<dim3((2 * NB * PP) / 256), dim3(256), 0, stream>>>(ssx, invx);
  k_gemm<<<dim3(PP / 128, PP / 128, NB), dim3(256), 0, stream>>>(xt, yt, invx, invy, S);
  k_rowstats<<<dim3(NB * PP), dim3(256), 0, stream>>>(S, dmin, rsum);
  k_colmax_part<<<dim3(PP / 256, NB, 6), dim3(256), 0, stream>>>(S, dmin, rsum, pcm);
  k_colmax_fin<<<dim3(PP / 256, NB), dim3(256), 0, stream>>>(pcm, cx);
  k_final<<<1, 64, 0, stream>>>(cx, (float*)d_out);
}

// Round 2
// 170.662 us; speedup vs baseline: 1.1219x; 1.1219x over previous
//
#include <hip/hip_runtime.h>
#include <stdint.h>

#define NB 8
#define CC 512
#define PP 2304
#define EPSF 1e-5f
#define NPC 12   // p-chunks for colmax
#define PCH 192  // p per chunk (NPC*PCH == PP)

typedef short bf16x8 __attribute__((ext_vector_type(8)));
typedef float f32x4 __attribute__((ext_vector_type(4)));

typedef __attribute__((address_space(3))) uint8_t lds8_t;
typedef __attribute__((address_space(1))) const uint8_t g8_t;

__device__ __forceinline__ void async16(void* lds, const void* g) {
  __builtin_amdgcn_global_load_lds((g8_t*)g, (lds8_t*)lds, 16, 0, 0);
}

__device__ __forceinline__ float bf2f(uint32_t b16) {
  return __uint_as_float(b16 << 16);
}
__device__ __forceinline__ uint32_t f2bf(float f) {  // RNE
  uint32_t u = __float_as_uint(f);
  return (u + 0x7fffu + ((u >> 16) & 1u)) >> 16;
}

// ---------------- K1: channel mean of target over (N,H,W) ----------------
__global__ __launch_bounds__(256) void k_chan_mean(const float* __restrict__ tgt,
                                                   float* __restrict__ mu) {
  const int c = blockIdx.x, t = threadIdx.x;
  float s = 0.f;
  for (int n = 0; n < NB; ++n) {
    const float* b = tgt + ((size_t)n * CC + c) * PP;
    for (int p = t; p < PP; p += 256) s += b[p];
  }
  for (int off = 32; off; off >>= 1) s += __shfl_down(s, off);
  __shared__ float red[4];
  if ((t & 63) == 0) red[t >> 6] = s;
  __syncthreads();
  if (t == 0) mu[c] = (red[0] + red[1] + red[2] + red[3]) * (1.0f / (NB * PP));
}

// ------- K2: center by mu, cast bf16, transpose [N][C][P]->[N][P][C], sumsq over C -------
__global__ __launch_bounds__(256) void k_center_cast(
    const float* __restrict__ pred, const float* __restrict__ tgt,
    const float* __restrict__ mu,
    uint16_t* __restrict__ xt, uint16_t* __restrict__ yt,
    float* __restrict__ ssx, float* __restrict__ ssy) {
  __shared__ uint32_t lt[64][33];   // [p][c-pair], +1 pad -> conflict-free
  __shared__ float red[4][64];
  const int p0 = blockIdx.x * 64, c0 = blockIdx.y * 64, n = blockIdx.z;
  const int t = threadIdx.x, lp = t & 63, cb = t >> 6;
  for (int which = 0; which < 2; ++which) {
    const float* in = which ? tgt : pred;
    uint16_t* out = which ? yt : xt;
    float* ss = which ? ssy : ssx;
    float sq = 0.f;
    uint32_t packs[8];
#pragma unroll
    for (int i = 0; i < 16; ++i) {
      const int c = c0 + cb * 16 + i;
      float v = in[((size_t)n * CC + c) * PP + p0 + lp] - mu[c];
      sq += v * v;
      uint32_t b = f2bf(v);
      if (i & 1) packs[i >> 1] |= b << 16; else packs[i >> 1] = b;
    }
#pragma unroll
    for (int j = 0; j < 8; ++j) lt[lp][cb * 8 + j] = packs[j];
    red[cb][lp] = sq;
    __syncthreads();
    if (t < 64)
      atomicAdd(&ss[(size_t)n * PP + p0 + t],
                red[0][t] + red[1][t] + red[2][t] + red[3][t]);
    // write-out: thread t -> row p0+(t>>2), 16 contiguous c's
    const int p = t >> 2, ch = t & 3;
    uint4 v0, v1;
    v0.x = lt[p][ch * 8 + 0]; v0.y = lt[p][ch * 8 + 1];
    v0.z = lt[p][ch * 8 + 2]; v0.w = lt[p][ch * 8 + 3];
    v1.x = lt[p][ch * 8 + 4]; v1.y = lt[p][ch * 8 + 5];
    v1.z = lt[p][ch * 8 + 6]; v1.w = lt[p][ch * 8 + 7];
    uint4* ob = (uint4*)(out + (((size_t)n * PP + p0 + p) * CC + c0 + ch * 16));
    ob[0] = v0; ob[1] = v1;
    __syncthreads();
  }
}

// ---------------- K3: batched GEMM S[p][q] = sum_c X[p][c]*Y[q][c], scaled epilogue ----------------
// global_load_lds staging with pre-swizzled global source (LDS dest linear);
// read side uses kb ^ ((row&7)<<4) -> conflict-free, same involution both sides.
__global__ __launch_bounds__(256) void k_gemm(
    const uint16_t* __restrict__ xt, const uint16_t* __restrict__ yt,
    const float* __restrict__ ssx, const float* __restrict__ ssy,
    uint16_t* __restrict__ S) {
  __shared__ uint16_t As[128 * 64];
  __shared__ uint16_t Bs[128 * 64];
  // XCD-aware swizzle: nwg = 18*18*8 = 2592, 324/XCD = exactly one batch/XCD
  int flat = blockIdx.x + 18 * blockIdx.y + 324 * blockIdx.z;
  flat = (flat & 7) * 324 + (flat >> 3);
  const int nb = flat / 324;
  const int rem = flat - nb * 324;
  const int byn = rem / 18;
  const int bxm = rem - byn * 18;
  const int m0 = bxm * 128, n0 = byn * 128;
  const int t = threadIdx.x, lane = t & 63, wid = t >> 6;
  const int wr = wid >> 1, wc = wid & 1;
  const uint16_t* Ax = xt + (size_t)nb * PP * CC;
  const uint16_t* By = yt + (size_t)nb * PP * CC;
  // staging geometry: wave w, chunk j covers rows (w*4+j)*8 .. +7 (1 KiB LDS)
  // lane l -> LDS row_in_chunk = l>>3, linear slot = l&7;
  // source slot = (l&7) ^ (l>>3)   (row&7 == l>>3 since base row % 8 == 0)
  const int lrow = lane >> 3;
  const int lswz = (lane & 7) ^ lrow;
  const uint16_t* gA[4];
  const uint16_t* gB[4];
#pragma unroll
  for (int j = 0; j < 4; ++j) {
    const int row = (wid * 4 + j) * 8 + lrow;
    gA[j] = Ax + (size_t)(m0 + row) * CC + lswz * 8;
    gB[j] = By + (size_t)(n0 + row) * CC + lswz * 8;
  }
  f32x4 acc[4][4];
#pragma unroll
  for (int i = 0; i < 4; ++i)
#pragma unroll
    for (int j = 0; j < 4; ++j) acc[i][j] = (f32x4){0.f, 0.f, 0.f, 0.f};

  for (int k0 = 0; k0 < CC; k0 += 64) {
    __syncthreads();
#pragma unroll
    for (int j = 0; j < 4; ++j) {
      async16(As + (wid * 4 + j) * 512, gA[j] + k0);
      async16(Bs + (wid * 4 + j) * 512, gB[j] + k0);
    }
    __syncthreads();   // drains vmcnt + lgkm before compute
#pragma unroll
    for (int kk = 0; kk < 2; ++kk) {
      const int kb = kk * 64 + (lane >> 4) * 16;  // byte offset of this lane's 8 bf16
      bf16x8 af[4], bfr[4];
#pragma unroll
      for (int mi = 0; mi < 4; ++mi) {
        const int row = wr * 64 + mi * 16 + (lane & 15);
        af[mi] = *(const bf16x8*)((const char*)As + row * 128 + (kb ^ ((row & 7) << 4)));
      }
#pragma unroll
      for (int ni = 0; ni < 4; ++ni) {
        const int row = wc * 64 + ni * 16 + (lane & 15);
        bfr[ni] = *(const bf16x8*)((const char*)Bs + row * 128 + (kb ^ ((row & 7) << 4)));
      }
#pragma unroll
      for (int mi = 0; mi < 4; ++mi)
#pragma unroll
        for (int ni = 0; ni < 4; ++ni)
          acc[mi][ni] = __builtin_amdgcn_mfma_f32_16x16x32_bf16(
              af[mi], bfr[ni], acc[mi][ni], 0, 0, 0);
    }
  }
  // epilogue: inverse norms computed inline from sumsq, write bf16 cosine
  const float* rsp = ssx + (size_t)nb * PP;
  const float* csp = ssy + (size_t)nb * PP;
  float rinv[4][4], cinv[4];
#pragma unroll
  for (int mi = 0; mi < 4; ++mi)
#pragma unroll
    for (int r = 0; r < 4; ++r)
      rinv[mi][r] = 1.0f / fmaxf(sqrtf(rsp[m0 + wr * 64 + mi * 16 + (lane >> 4) * 4 + r]), 1e-12f);
#pragma unroll
  for (int ni = 0; ni < 4; ++ni)
    cinv[ni] = 1.0f / fmaxf(sqrtf(csp[n0 + wc * 64 + ni * 16 + (lane & 15)]), 1e-12f);
  uint16_t* Sp = S + (size_t)nb * PP * PP;
#pragma unroll
  for (int mi = 0; mi < 4; ++mi) {
#pragma unroll
    for (int r = 0; r < 4; ++r) {
      const int grow = m0 + wr * 64 + mi * 16 + (lane >> 4) * 4 + r;
      uint16_t* rowp = Sp + (size_t)grow * PP + n0 + wc * 64 + (lane & 15);
#pragma unroll
      for (int ni = 0; ni < 4; ++ni) {
        float v = acc[mi][ni][r] * rinv[mi][r] * cinv[ni];
        rowp[ni * 16] = (uint16_t)f2bf(v);
      }
    }
  }
}

// ---------------- K4: per-row (n,p): dmin = 1 - max_q cos ; rowsum = sum_q w ----------------
__global__ __launch_bounds__(256) void k_rowstats(const uint16_t* __restrict__ S,
                                                  float* __restrict__ dmin,
                                                  float* __restrict__ rsum) {
  const int row = blockIdx.x;  // n*PP + p
  const uint2* Sp = (const uint2*)(S + (size_t)row * PP);
  __shared__ __align__(16) float cosr[PP];
  __shared__ float reda[4], redb[4];
  const int t = threadIdx.x;
  float mx = -2.f;
  for (int i = t; i < PP / 4; i += 256) {
    uint2 u = Sp[i];
    float a = bf2f(u.x & 0xffffu), b = bf2f(u.x >> 16);
    float c = bf2f(u.y & 0xffffu), d = bf2f(u.y >> 16);
    *(float4*)&cosr[4 * i] = make_float4(a, b, c, d);
    mx = fmaxf(fmaxf(mx, fmaxf(a, b)), fmaxf(c, d));
  }
  for (int off = 32; off; off >>= 1) mx = fmaxf(mx, __shfl_down(mx, off));
  if ((t & 63) == 0) reda[t >> 6] = mx;
  __syncthreads();
  mx = fmaxf(fmaxf(reda[0], reda[1]), fmaxf(reda[2], reda[3]));
  const float dm = 1.0f - mx;
  const float sc = 2.0f / (dm + EPSF);  // (1-dist_tilde)/0.5 = (cos-mx+eps)*sc
  float s = 0.f;
  for (int i = t; i < PP; i += 256) s += __expf((cosr[i] - mx + EPSF) * sc);
  for (int off = 32; off; off >>= 1) s += __shfl_down(s, off);
  if ((t & 63) == 0) redb[t >> 6] = s;
  __syncthreads();
  if (t == 0) { dmin[row] = dm; rsum[row] = redb[0] + redb[1] + redb[2] + redb[3]; }
}

// ---------------- K5a: partial colmax over p-chunks of cx = w/rowsum ----------------
__global__ __launch_bounds__(256) void k_colmax_part(const uint16_t* __restrict__ S,
                                                     const float* __restrict__ dmin,
                                                     const float* __restrict__ rsum,
                                                     float* __restrict__ pcm) {
  const int n = blockIdx.y, pc = blockIdx.z, t = threadIdx.x;
  const int q2 = blockIdx.x * 512 + 2 * t;  // this thread's column pair
  __shared__ float lmx[PCH], lsc[PCH], lri[PCH];
  const float* dmn = dmin + (size_t)n * PP + pc * PCH;
  const float* rsn = rsum + (size_t)n * PP + pc * PCH;
  for (int i = t; i < PCH; i += 256) {
    float dm = dmn[i];
    lmx[i] = 1.0f - dm - EPSF;
    lsc[i] = 2.0f / (dm + EPSF);
    lri[i] = 1.0f / rsn[i];
  }
  __syncthreads();
  if (q2 >= PP) return;
  const uint32_t* Sn =
      (const uint32_t*)(S + (size_t)n * PP * PP + (size_t)pc * PCH * PP + q2);
  float b0 = 0.f, b1 = 0.f;
#pragma unroll 8
  for (int p = 0; p < PCH; ++p) {
    uint32_t u = Sn[(size_t)p * (PP / 2)];
    float mxv = lmx[p], scv = lsc[p], riv = lri[p];
    b0 = fmaxf(b0, __expf((bf2f(u & 0xffffu) - mxv) * scv) * riv);
    b1 = fmaxf(b1, __expf((bf2f(u >> 16) - mxv) * scv) * riv);
  }
  float* o = pcm + ((size_t)n * NPC + pc) * PP + q2;
  o[0] = b0; o[1] = b1;
}

// ---------------- K5b: finish colmax, sum over q, accumulate per-n ----------------
__global__ __launch_bounds__(256) void k_colmax_fin(const float* __restrict__ pcm,
                                                    float* __restrict__ cxacc) {
  const int n = blockIdx.y, t = threadIdx.x;
  const int q = blockIdx.x * 256 + t;
  float best = 0.f;
#pragma unroll
  for (int c = 0; c < NPC; ++c) best = fmaxf(best, pcm[((size_t)n * NPC + c) * PP + q]);
  float s = best;
  for (int off = 32; off; off >>= 1) s += __shfl_down(s, off);
  __shared__ float red[4];
  if ((t & 63) == 0) red[t >> 6] = s;
  __syncthreads();
  if (t == 0) atomicAdd(&cxacc[n], red[0] + red[1] + red[2] + red[3]);
}

// ---------------- K6: final loss ----------------
__global__ void k_final(const float* __restrict__ cxacc, float* __restrict__ out) {
  if (threadIdx.x == 0 && blockIdx.x == 0) {
    float s = 0.f;
    for (int n = 0; n < NB; ++n) {
      float cx = cxacc[n] * (1.0f / PP);
      s += -logf(cx + EPSF);
    }
    out[0] = s * (1.0f / NB);
  }
}

extern "C" void kernel_launch(void* const* d_in, const int* in_sizes, int n_in,
                              void* d_out, int out_size, void* d_ws, size_t ws_size,
                              hipStream_t stream) {
  const float* pred = (const float*)d_in[0];
  const float* tgt  = (const float*)d_in[1];
  float* W = (float*)d_ws;
  // workspace layout (float indices)
  float* mu   = W + 0;        // 512
  float* ssx  = W + 1024;     // 18432
  float* ssy  = W + 19456;    // 18432  (contiguous with ssx)
  float* cx   = W + 37888;    // 8
  float* dmin = W + 75264;    // 18432
  float* rsum = W + 93696;    // 18432
  uint16_t* xt = (uint16_t*)(W + 223744);          // 9437184 bf16
  uint16_t* yt = xt + (size_t)NB * PP * CC;        // 9437184 bf16
  uint16_t* S  = yt + (size_t)NB * PP * CC;        // 42467328 bf16
  float* pcm = (float*)xt;  // aliases xt (dead after gemm); 8*12*2304 floats

  // zero atomic accumulators: ssx, ssy, cx
  hipMemsetAsync(W + 1024, 0, (36872) * sizeof(float), stream);

  k_chan_mean<<<dim3(CC), dim3(256), 0, stream>>>(tgt, mu);
  k_center_cast<<<dim3(PP / 64, CC / 64, NB), dim3(256), 0, stream>>>(
      pred, tgt, mu, xt, yt, ssx, ssy);
  k_gemm<<<dim3(PP / 128, PP / 128, NB), dim3(256), 0, stream>>>(xt, yt, ssx, ssy, S);
  k_rowstats<<<dim3(NB * PP), dim3(256), 0, stream>>>(S, dmin, rsum);
  k_colmax_part<<<dim3((PP + 511) / 512, NB, NPC), dim3(256), 0, stream>>>(
      S, dmin, rsum, pcm);
  k_colmax_fin<<<dim3(PP / 256, NB), dim3(256), 0, stream>>>(pcm, cx);
  k_final<<<1, 64, 0, stream>>>(cx, (float*)d_out);
}

// Round 3
// 159.692 us; speedup vs baseline: 1.1990x; 1.0687x over previous
//
#include <hip/hip_runtime.h>
#include <stdint.h>

#define NB 8
#define CC 512
#define PP 2304
#define EPSF 1e-5f
#define NPC 12   // p-chunks for colmax
#define PCH 192  // p per chunk (NPC*PCH == PP)

typedef short bf16x8 __attribute__((ext_vector_type(8)));
typedef float f32x4 __attribute__((ext_vector_type(4)));

typedef __attribute__((address_space(3))) uint8_t lds8_t;
typedef __attribute__((address_space(1))) const uint8_t g8_t;

__device__ __forceinline__ void async16(void* lds, const void* g) {
  __builtin_amdgcn_global_load_lds((g8_t*)g, (lds8_t*)lds, 16, 0, 0);
}

__device__ __forceinline__ float bf2f(uint32_t b16) {
  return __uint_as_float(b16 << 16);
}
__device__ __forceinline__ uint32_t f2bf(float f) {  // RNE
  uint32_t u = __float_as_uint(f);
  return (u + 0x7fffu + ((u >> 16) & 1u)) >> 16;
}

template <int N>
__device__ __forceinline__ void vmwait() {
  if constexpr (N == 0) asm volatile("s_waitcnt vmcnt(0)" ::: "memory");
  else if constexpr (N == 4) asm volatile("s_waitcnt vmcnt(4)" ::: "memory");
  else if constexpr (N == 6) asm volatile("s_waitcnt vmcnt(6)" ::: "memory");
  else if constexpr (N == 8) asm volatile("s_waitcnt vmcnt(8)" ::: "memory");
  // N < 0: no wait
}

// ---------------- K1: channel mean of target over (N,H,W) ----------------
__global__ __launch_bounds__(256) void k_chan_mean(const float* __restrict__ tgt,
                                                   float* __restrict__ mu) {
  const int c = blockIdx.x, t = threadIdx.x;
  float s = 0.f;
  for (int n = 0; n < NB; ++n) {
    const float* b = tgt + ((size_t)n * CC + c) * PP;
    for (int p = t; p < PP; p += 256) s += b[p];
  }
  for (int off = 32; off; off >>= 1) s += __shfl_down(s, off);
  __shared__ float red[4];
  if ((t & 63) == 0) red[t >> 6] = s;
  __syncthreads();
  if (t == 0) mu[c] = (red[0] + red[1] + red[2] + red[3]) * (1.0f / (NB * PP));
}

// ------- K2: center by mu, cast bf16, transpose [N][C][P]->[N][P][C], sumsq over C -------
__global__ __launch_bounds__(256) void k_center_cast(
    const float* __restrict__ pred, const float* __restrict__ tgt,
    const float* __restrict__ mu,
    uint16_t* __restrict__ xt, uint16_t* __restrict__ yt,
    float* __restrict__ ssx, float* __restrict__ ssy) {
  __shared__ uint32_t lt[64][33];   // [p][c-pair], +1 pad -> conflict-free
  __shared__ float red[4][64];
  const int p0 = blockIdx.x * 64, c0 = blockIdx.y * 64, n = blockIdx.z;
  const int t = threadIdx.x, lp = t & 63, cb = t >> 6;
  for (int which = 0; which < 2; ++which) {
    const float* in = which ? tgt : pred;
    uint16_t* out = which ? yt : xt;
    float* ss = which ? ssy : ssx;
    float sq = 0.f;
    uint32_t packs[8];
#pragma unroll
    for (int i = 0; i < 16; ++i) {
      const int c = c0 + cb * 16 + i;
      float v = in[((size_t)n * CC + c) * PP + p0 + lp] - mu[c];
      sq += v * v;
      uint32_t b = f2bf(v);
      if (i & 1) packs[i >> 1] |= b << 16; else packs[i >> 1] = b;
    }
#pragma unroll
    for (int j = 0; j < 8; ++j) lt[lp][cb * 8 + j] = packs[j];
    red[cb][lp] = sq;
    __syncthreads();
    if (t < 64)
      atomicAdd(&ss[(size_t)n * PP + p0 + t],
                red[0][t] + red[1][t] + red[2][t] + red[3][t]);
    // write-out: thread t -> row p0+(t>>2), 16 contiguous c's
    const int p = t >> 2, ch = t & 3;
    uint4 v0, v1;
    v0.x = lt[p][ch * 8 + 0]; v0.y = lt[p][ch * 8 + 1];
    v0.z = lt[p][ch * 8 + 2]; v0.w = lt[p][ch * 8 + 3];
    v1.x = lt[p][ch * 8 + 4]; v1.y = lt[p][ch * 8 + 5];
    v1.z = lt[p][ch * 8 + 6]; v1.w = lt[p][ch * 8 + 7];
    uint4* ob = (uint4*)(out + (((size_t)n * PP + p0 + p) * CC + c0 + ch * 16));
    ob[0] = v0; ob[1] = v1;
    __syncthreads();
  }
}

// ---------------- K3: 256x256-tile 8-phase GEMM (T2+T3+T4+T5 per §5 template) ----------------
// S[p][q] = xhat[p]·yhat[q]; A=xt rows, B=yt rows (both [P][C] bf16).
// LDS: lds[buf 2][region: A0,A1,B0,B1][128x64 bf16]. Phases = block C-quadrants:
// phase(qm,qn) reads ONLY A-half qm + B-half qn -> per-half liveness for prefetch.

__device__ __forceinline__ void stage_half(uint16_t* reg, const uint16_t* g, int tid) {
  // 128 rows x 64 k half-tile: 2 x global_load_lds dwordx4 per thread (512 thr)
  async16((char*)reg + tid * 16, g);
  async16((char*)reg + tid * 16 + 8192, g + 64 * CC);
}

template <int QM, int QN, bool LOADA, bool STG, int VM>
__device__ __forceinline__ void phase(const uint16_t (*R)[8192],
                                      uint16_t* sdst, const uint16_t* ssrc,
                                      int tid, int lane, int wr, int wcn,
                                      bf16x8 (&af)[4][2], f32x4 (&acc)[2][4][2][2]) {
  if (LOADA) {
#pragma unroll
    for (int i = 0; i < 4; ++i) {
      const int rh = wr * 64 + i * 16 + (lane & 15);
      const char* base = (const char*)R[QM] + rh * 128;
      const int sw = (rh & 7) << 4;
#pragma unroll
      for (int kk = 0; kk < 2; ++kk)
        af[i][kk] = *(const bf16x8*)(base + ((kk * 64 + (lane >> 4) * 16) ^ sw));
    }
  }
  bf16x8 bf[2][2];
#pragma unroll
  for (int j = 0; j < 2; ++j) {
    const int rh = wcn * 32 + j * 16 + (lane & 15);
    const char* base = (const char*)R[2 + QN] + rh * 128;
    const int sw = (rh & 7) << 4;
#pragma unroll
    for (int kk = 0; kk < 2; ++kk)
      bf[j][kk] = *(const bf16x8*)(base + ((kk * 64 + (lane >> 4) * 16) ^ sw));
  }
  if (STG) stage_half(sdst, ssrc, tid);
  __builtin_amdgcn_s_barrier();
  asm volatile("s_waitcnt lgkmcnt(0)" ::: "memory");
  __builtin_amdgcn_s_setprio(1);
#pragma unroll
  for (int i = 0; i < 4; ++i)
#pragma unroll
    for (int j = 0; j < 2; ++j)
#pragma unroll
      for (int kk = 0; kk < 2; ++kk)
        acc[QM][i][QN][j] = __builtin_amdgcn_mfma_f32_16x16x32_bf16(
            af[i][kk], bf[j][kk], acc[QM][i][QN][j], 0, 0, 0);
  __builtin_amdgcn_s_setprio(0);
  vmwait<VM>();
  __builtin_amdgcn_s_barrier();
}

__global__ __launch_bounds__(512, 2) void k_gemm(
    const uint16_t* __restrict__ xt, const uint16_t* __restrict__ yt,
    const float* __restrict__ ssx, const float* __restrict__ ssy,
    uint16_t* __restrict__ S) {
  __shared__ uint16_t lds[2][4][8192];  // 128 KiB
  // XCD swizzle: 648 blocks = 81 per XCD (648 % 8 == 0 -> bijective)
  int flat = blockIdx.x + 9 * blockIdx.y + 81 * blockIdx.z;
  flat = (flat & 7) * 81 + (flat >> 3);
  const int nb = flat / 81;
  const int rem = flat - nb * 81;
  const int m0 = (rem % 9) * 256, n0 = (rem / 9) * 256;
  const int tid = threadIdx.x, lane = tid & 63, wid = tid >> 6;
  const int wr = wid >> 2, wcn = wid & 3;
  const uint16_t* Ax = xt + (size_t)nb * PP * CC;
  const uint16_t* By = yt + (size_t)nb * PP * CC;
  // staging source: thread t -> row t>>3, pre-swizzled slot (t&7)^((t>>3)&7)
  const int lswz = (tid & 7) ^ ((tid >> 3) & 7);
  const uint16_t* gAb = Ax + (size_t)(m0 + (tid >> 3)) * CC + lswz * 8;
  const uint16_t* gBb = By + (size_t)(n0 + (tid >> 3)) * CC + lswz * 8;

  f32x4 acc[2][4][2][2];
#pragma unroll
  for (int a = 0; a < 2; ++a)
#pragma unroll
    for (int b = 0; b < 4; ++b)
#pragma unroll
      for (int c = 0; c < 2; ++c)
#pragma unroll
        for (int d = 0; d < 2; ++d) acc[a][b][c][d] = (f32x4){0.f, 0.f, 0.f, 0.f};

  // prologue: as-if ph3,4(kt-2), ph1,2(kt-1), ph3,4(kt-1)
  stage_half(lds[0][0], gAb, tid);              // A0(0)
  stage_half(lds[0][2], gBb, tid);              // B0(0)
  stage_half(lds[0][1], gAb + 128 * CC, tid);   // A1(0)
  stage_half(lds[0][3], gBb + 128 * CC, tid);   // B1(0)
  stage_half(lds[1][0], gAb + 64, tid);         // A0(1)
  stage_half(lds[1][2], gBb + 64, tid);         // B0(1)
  vmwait<8>();                                   // A0(0),B0(0) resident
  __builtin_amdgcn_s_barrier();

  bf16x8 af[4][2];
  for (int kt = 0; kt < 6; ++kt) {
    const int cur = kt & 1;
    const uint16_t(*R)[8192] = lds[cur];
    uint16_t(*Wn)[8192] = lds[cur ^ 1];
    uint16_t(*Wc)[8192] = lds[cur];
    const int ko = (kt + 1) * 64;
    // ph1(0,0): stage A1(kt+1); vmcnt(6) guards next phase's B1(kt)
    phase<0, 0, true, true, 6>(R, Wn[1], gAb + 128 * CC + ko, tid, lane, wr, wcn, af, acc);
    // ph2(0,1): stage B1(kt+1)
    phase<0, 1, false, true, -1>(R, Wn[3], gBb + 128 * CC + ko, tid, lane, wr, wcn, af, acc);
    // ph3(1,0): stage A0(kt+2) into freed A0 of current buf
    phase<1, 0, true, true, -1>(R, Wc[0], gAb + ko + 64, tid, lane, wr, wcn, af, acc);
    // ph4(1,1): stage B0(kt+2); vmcnt(8) guards next tile's A0,B0
    phase<1, 1, false, true, 8>(R, Wc[2], gBb + ko + 64, tid, lane, wr, wcn, af, acc);
  }
  {  // kt = 6 (cur = 0): last A1/B1 stages; drain ramps 8->4
    const uint16_t(*R)[8192] = lds[0];
    phase<0, 0, true, true, 6>(R, lds[1][1], gAb + 128 * CC + 7 * 64, tid, lane, wr, wcn, af, acc);
    phase<0, 1, false, true, -1>(R, lds[1][3], gBb + 128 * CC + 7 * 64, tid, lane, wr, wcn, af, acc);
    phase<1, 0, true, false, -1>(R, nullptr, nullptr, tid, lane, wr, wcn, af, acc);
    phase<1, 1, false, false, 4>(R, nullptr, nullptr, tid, lane, wr, wcn, af, acc);
  }
  {  // kt = 7 (cur = 1): final tile, drain to 0 after ph1
    const uint16_t(*R)[8192] = lds[1];
    phase<0, 0, true, false, 0>(R, nullptr, nullptr, tid, lane, wr, wcn, af, acc);
    phase<0, 1, false, false, -1>(R, nullptr, nullptr, tid, lane, wr, wcn, af, acc);
    phase<1, 0, true, false, -1>(R, nullptr, nullptr, tid, lane, wr, wcn, af, acc);
    phase<1, 1, false, false, -1>(R, nullptr, nullptr, tid, lane, wr, wcn, af, acc);
  }

  // epilogue: scale by inverse norms, write bf16 cosine
  const float* rsp = ssx + (size_t)nb * PP + m0;
  const float* csp = ssy + (size_t)nb * PP + n0;
  uint16_t* Sp = S + (size_t)nb * PP * PP;
  float cinv[2][2];
#pragma unroll
  for (int qn = 0; qn < 2; ++qn)
#pragma unroll
    for (int j = 0; j < 2; ++j)
      cinv[qn][j] =
          1.0f / fmaxf(sqrtf(csp[qn * 128 + wcn * 32 + j * 16 + (lane & 15)]), 1e-12f);
#pragma unroll
  for (int qm = 0; qm < 2; ++qm)
#pragma unroll
    for (int i = 0; i < 4; ++i)
#pragma unroll
      for (int r = 0; r < 4; ++r) {
        const int row = qm * 128 + wr * 64 + i * 16 + (lane >> 4) * 4 + r;
        const float ri = 1.0f / fmaxf(sqrtf(rsp[row]), 1e-12f);
        uint16_t* orow = Sp + (size_t)(m0 + row) * PP + n0;
#pragma unroll
        for (int qn = 0; qn < 2; ++qn)
#pragma unroll
          for (int j = 0; j < 2; ++j)
            orow[qn * 128 + wcn * 32 + j * 16 + (lane & 15)] =
                (uint16_t)f2bf(acc[qm][i][qn][j][r] * ri * cinv[qn][j]);
      }
}

// ---------------- K4: per-row (n,p): dmin = 1 - max_q cos ; rowsum = sum_q w ----------------
__global__ __launch_bounds__(256) void k_rowstats(const uint16_t* __restrict__ S,
                                                  float* __restrict__ dmin,
                                                  float* __restrict__ rsum) {
  const int row = blockIdx.x;  // n*PP + p
  const uint2* Sp = (const uint2*)(S + (size_t)row * PP);
  __shared__ __align__(16) float cosr[PP];
  __shared__ float reda[4], redb[4];
  const int t = threadIdx.x;
  float mx = -2.f;
  for (int i = t; i < PP / 4; i += 256) {
    uint2 u = Sp[i];
    float a = bf2f(u.x & 0xffffu), b = bf2f(u.x >> 16);
    float c = bf2f(u.y & 0xffffu), d = bf2f(u.y >> 16);
    *(float4*)&cosr[4 * i] = make_float4(a, b, c, d);
    mx = fmaxf(fmaxf(mx, fmaxf(a, b)), fmaxf(c, d));
  }
  for (int off = 32; off; off >>= 1) mx = fmaxf(mx, __shfl_down(mx, off));
  if ((t & 63) == 0) reda[t >> 6] = mx;
  __syncthreads();
  mx = fmaxf(fmaxf(reda[0], reda[1]), fmaxf(reda[2], reda[3]));
  const float dm = 1.0f - mx;
  const float sc = 2.0f / (dm + EPSF);  // (1-dist_tilde)/0.5 = (cos-mx+eps)*sc
  float s = 0.f;
  for (int i = t; i < PP; i += 256) s += __expf((cosr[i] - mx + EPSF) * sc);
  for (int off = 32; off; off >>= 1) s += __shfl_down(s, off);
  if ((t & 63) == 0) redb[t >> 6] = s;
  __syncthreads();
  if (t == 0) { dmin[row] = dm; rsum[row] = redb[0] + redb[1] + redb[2] + redb[3]; }
}

// ---------------- K5a: partial colmax over p-chunks of cx = w/rowsum ----------------
__global__ __launch_bounds__(256) void k_colmax_part(const uint16_t* __restrict__ S,
                                                     const float* __restrict__ dmin,
                                                     const float* __restrict__ rsum,
                                                     float* __restrict__ pcm) {
  const int n = blockIdx.y, pc = blockIdx.z, t = threadIdx.x;
  const int q2 = blockIdx.x * 512 + 2 * t;  // this thread's column pair
  __shared__ float lmx[PCH], lsc[PCH], lri[PCH];
  const float* dmn = dmin + (size_t)n * PP + pc * PCH;
  const float* rsn = rsum + (size_t)n * PP + pc * PCH;
  for (int i = t; i < PCH; i += 256) {
    float dm = dmn[i];
    lmx[i] = 1.0f - dm - EPSF;
    lsc[i] = 2.0f / (dm + EPSF);
    lri[i] = 1.0f / rsn[i];
  }
  __syncthreads();
  if (q2 >= PP) return;
  const uint32_t* Sn =
      (const uint32_t*)(S + (size_t)n * PP * PP + (size_t)pc * PCH * PP + q2);
  float b0 = 0.f, b1 = 0.f;
#pragma unroll 8
  for (int p = 0; p < PCH; ++p) {
    uint32_t u = Sn[(size_t)p * (PP / 2)];
    float mxv = lmx[p], scv = lsc[p], riv = lri[p];
    b0 = fmaxf(b0, __expf((bf2f(u & 0xffffu) - mxv) * scv) * riv);
    b1 = fmaxf(b1, __expf((bf2f(u >> 16) - mxv) * scv) * riv);
  }
  float* o = pcm + ((size_t)n * NPC + pc) * PP + q2;
  o[0] = b0; o[1] = b1;
}

// ---------------- K5b: finish colmax, sum over q, accumulate per-n ----------------
__global__ __launch_bounds__(256) void k_colmax_fin(const float* __restrict__ pcm,
                                                    float* __restrict__ cxacc) {
  const int n = blockIdx.y, t = threadIdx.x;
  const int q = blockIdx.x * 256 + t;
  float best = 0.f;
#pragma unroll
  for (int c = 0; c < NPC; ++c) best = fmaxf(best, pcm[((size_t)n * NPC + c) * PP + q]);
  float s = best;
  for (int off = 32; off; off >>= 1) s += __shfl_down(s, off);
  __shared__ float red[4];
  if ((t & 63) == 0) red[t >> 6] = s;
  __syncthreads();
  if (t == 0) atomicAdd(&cxacc[n], red[0] + red[1] + red[2] + red[3]);
}

// ---------------- K6: final loss ----------------
__global__ void k_final(const float* __restrict__ cxacc, float* __restrict__ out) {
  if (threadIdx.x == 0 && blockIdx.x == 0) {
    float s = 0.f;
    for (int n = 0; n < NB; ++n) {
      float cx = cxacc[n] * (1.0f / PP);
      s += -logf(cx + EPSF);
    }
    out[0] = s * (1.0f / NB);
  }
}

extern "C" void kernel_launch(void* const* d_in, const int* in_sizes, int n_in,
                              void* d_out, int out_size, void* d_ws, size_t ws_size,
                              hipStream_t stream) {
  const float* pred = (const float*)d_in[0];
  const float* tgt  = (const float*)d_in[1];
  float* W = (float*)d_ws;
  // workspace layout (float indices)
  float* mu   = W + 0;        // 512
  float* ssx  = W + 1024;     // 18432
  float* ssy  = W + 19456;    // 18432  (contiguous with ssx)
  float* cx   = W + 37888;    // 8
  float* dmin = W + 75264;    // 18432
  float* rsum = W + 93696;    // 18432
  uint16_t* xt = (uint16_t*)(W + 223744);          // 9437184 bf16
  uint16_t* yt = xt + (size_t)NB * PP * CC;        // 9437184 bf16
  uint16_t* S  = yt + (size_t)NB * PP * CC;        // 42467328 bf16
  float* pcm = (float*)xt;  // aliases xt (dead after gemm); 8*12*2304 floats

  // zero atomic accumulators: ssx, ssy, cx
  hipMemsetAsync(W + 1024, 0, (36872) * sizeof(float), stream);

  k_chan_mean<<<dim3(CC), dim3(256), 0, stream>>>(tgt, mu);
  k_center_cast<<<dim3(PP / 64, CC / 64, NB), dim3(256), 0, stream>>>(
      pred, tgt, mu, xt, yt, ssx, ssy);
  k_gemm<<<dim3(9, 9, NB), dim3(512), 0, stream>>>(xt, yt, ssx, ssy, S);
  k_rowstats<<<dim3(NB * PP), dim3(256), 0, stream>>>(S, dmin, rsum);
  k_colmax_part<<<dim3((PP + 511) / 512, NB, NPC), dim3(256), 0, stream>>>(
      S, dmin, rsum, pcm);
  k_colmax_fin<<<dim3(PP / 256, NB), dim3(256), 0, stream>>>(pcm, cx);
  k_final<<<1, 64, 0, stream>>>(cx, (float*)d_out);
}